// Round 10
// baseline (1926.153 us; speedup 1.0000x reference)
//
#include <hip/hip_runtime.h>
#include <stdint.h>
#include <math.h>

// Instant-NGP hash-grid + MLP, FULLY FUSED.
// Block = 256 thr / 4 waves / 64 points. Wave sq encodes levels sq*8..sq*8+7
// of all 64 points (level uniform per iteration -> wave-uniform dense/hash
// branch, corner-pair merged gathers). One barrier. Then MLP is wave-local:
// wave w owns points w*16..w*16+15 (swapped-operand layer1 -> h1^T, b64
// stores), W fragments read per-use from L2-hot prebaked wimg.
// No feats round-trip, no W LDS staging, 24KB LDS.

#define NLV 32
#define LOG2T 19
#define TSZ (1u << LOG2T)
#define TMASK (TSZ - 1u)
#define PRIME2 2654435761u
#define PRIME3 805459861u

typedef float v2f __attribute__((ext_vector_type(2)));
typedef float f32x4 __attribute__((ext_vector_type(4)));
typedef float f32x4u __attribute__((ext_vector_type(4), aligned(8)));
typedef short bf16x8 __attribute__((ext_vector_type(8)));
typedef uint32_t u32x4 __attribute__((ext_vector_type(4)));
typedef uint32_t u32x2 __attribute__((ext_vector_type(2)));

struct Scales { float s[NLV]; };

__device__ __forceinline__ uint32_t pack_bf16(float a, float b) {
  uint32_t ua = __float_as_uint(a), ub = __float_as_uint(b);
  ua = (ua + 0x7fffu + ((ua >> 16) & 1u)) >> 16;
  ub = (ub + 0x7fffu + ((ub >> 16) & 1u)) >> 16;
  return ua | (ub << 16);
}
__device__ __forceinline__ uint16_t bf16_rne(float a) {
  uint32_t u = __float_as_uint(a);
  u = (u + 0x7fffu + ((u >> 16) & 1u)) >> 16;
  return (uint16_t)u;
}

// W1 -> wimg[0..16KB): byte addr n*128 + ((k*2)^((n&7)<<4))
// W2 -> wimg[16KB..48KB): byte addr 16384 + n*256 + ((k*2)^((n&7)<<4))
__global__ __launch_bounds__(512) void prep_kernel(
    const float* __restrict__ W1, const float* __restrict__ W2,
    uint16_t* __restrict__ wimg)
{
  int i = (int)blockIdx.x * 512 + (int)threadIdx.x;
  if (i < 8192) {
    int k = i >> 7, n = i & 127;
    wimg[(n * 128 + ((k * 2) ^ ((n & 7) << 4))) >> 1] = bf16_rne(W1[i]);
  } else if (i < 24576) {
    int t = i - 8192;
    int k = t >> 7, n = t & 127;
    wimg[(16384 + n * 256 + ((k * 2) ^ ((n & 7) << 4))) >> 1] = bf16_rne(W2[t]);
  }
}

__device__ __forceinline__ uint32_t encode_level(
    float scale, uint32_t r, bool dense, const v2f* __restrict__ embl,
    float xv, float yv, float zv)
{
  // EXACT replication of reference rounding: mul RN then add RN (no FMA!)
  float px = __fadd_rn(__fmul_rn(xv, scale), 0.5f);
  float py = __fadd_rn(__fmul_rn(yv, scale), 0.5f);
  float pz = __fadd_rn(__fmul_rn(zv, scale), 0.5f);
  float bx = floorf(px), by = floorf(py), bz = floorf(pz);
  float fx = __fsub_rn(px, bx), fy = __fsub_rn(py, by), fz = __fsub_rn(pz, bz);
  uint32_t gx = (uint32_t)bx, gy = (uint32_t)by, gz = (uint32_t)bz;
  float wx0 = __fsub_rn(1.0f, fx), wx1 = fx;
  float wy0 = __fsub_rn(1.0f, fy), wy1 = fy;
  float wz0 = __fsub_rn(1.0f, fz), wz1 = fz;
  const uint32_t rr = r * r;

  float f0 = 0.0f, f1 = 0.0f;
  #pragma unroll
  for (int cp = 0; cp < 4; ++cp) {
    uint32_t cy = gy + (uint32_t)(cp & 1);
    uint32_t cz = gz + (uint32_t)(cp >> 1);
    float wyz = __fmul_rn((cp & 1) ? wy1 : wy0, (cp >> 1) ? wz1 : wz0);
    v2f e0, e1;
    if (dense) {
      uint32_t i0 = gx + cy * r + cz * rr;      // idx1 = idx0 + 1
      f32x4 e2 = *(const f32x4u*)&embl[i0];
      e0[0] = e2.x; e0[1] = e2.y; e1[0] = e2.z; e1[1] = e2.w;
    } else {
      uint32_t h = (cy * PRIME2) ^ (cz * PRIME3);
      uint32_t i0 = (gx ^ h) & TMASK;
      if (!(gx & 1u)) {                          // idx1 = idx0 ^ 1
        f32x4 e2 = *(const f32x4*)&embl[i0 & ~1u];
        bool odd = (i0 & 1u) != 0u;
        e0[0] = odd ? e2.z : e2.x; e0[1] = odd ? e2.w : e2.y;
        e1[0] = odd ? e2.x : e2.z; e1[1] = odd ? e2.y : e2.w;
      } else {
        uint32_t i1 = ((gx + 1u) ^ h) & TMASK;
        e0 = embl[i0];
        e1 = embl[i1];
      }
    }
    float w0 = __fmul_rn(wx0, wyz), w1 = __fmul_rn(wx1, wyz);
    f0 = fmaf(w0, e0[0], f0); f1 = fmaf(w0, e0[1], f1);
    f0 = fmaf(w1, e1[0], f0); f1 = fmaf(w1, e1[1], f1);
  }
  return pack_bf16(f0, f1);
}

__global__ __launch_bounds__(256) void fused_kernel(
    const float* __restrict__ x, const float* __restrict__ emb,
    const uint16_t* __restrict__ wimg,
    const float* __restrict__ b1, const float* __restrict__ b2,
    const float* __restrict__ W3, const float* __restrict__ b3,
    float* __restrict__ out, int count, Scales sc)
{
  __shared__ char lds[24576];
  char* xb = lds;            // 64 pts x 128B : X bf16x64, swizzled rows
  char* hb = lds + 8192;     // 64 pts x 256B : h1 bf16x128, swizzled rows

  const int tid = (int)threadIdx.x;
  const int sp = tid & 63;       // encode: this thread's point row
  const int sq = tid >> 6;       // encode: level octave (wave-uniform)
  const int base = (int)blockIdx.x * 64;

  // ---- encode phase: levels sq*8..sq*8+7 of point sp ----
  {
    int gp = base + sp;
    int src = (gp < count) ? gp : 0;
    float xv = x[3 * src + 0], yv = x[3 * src + 1], zv = x[3 * src + 2];
    const int l0 = __builtin_amdgcn_readfirstlane(sq * 8);
    uint32_t f[8];
    #pragma unroll
    for (int i = 0; i < 8; ++i) {
      const int l = l0 + i;                       // wave-uniform
      const float scale = sc.s[l];
      const uint32_t r = 1u << l;
      const bool dense = (l <= 6);
      const v2f* embl = (const v2f*)(emb + ((size_t)l << (LOG2T + 1)));
      f[i] = encode_level(scale, r, dense, embl, xv, yv, zv);
    }
    u32x4 v0, v1;
    v0.x = f[0]; v0.y = f[1]; v0.z = f[2]; v0.w = f[3];
    v1.x = f[4]; v1.y = f[5]; v1.z = f[6]; v1.w = f[7];
    int sw = (sp & 7) << 4;
    *(u32x4*)(xb + sp * 128 + ((sq * 32 +  0) ^ sw)) = v0;
    *(u32x4*)(xb + sp * 128 + ((sq * 32 + 16) ^ sw)) = v1;
  }
  __syncthreads();

  // ---- MLP phase: wave-local (wave w owns points w*16..w*16+15) ----
  const int lane = tid & 63;
  const int w = tid >> 6;
  const int col = lane & 15;
  const int kh = lane >> 4;
  const int pp = w * 16 + col;
  const char* wbytes = (const char*)wimg;

  // layer 1, operand-swapped: D = W1^T x X = h1^T
  bf16x8 xa[2];
  #pragma unroll
  for (int kt = 0; kt < 2; ++kt)
    xa[kt] = *(const bf16x8*)(xb + pp * 128 +
                 ((kt * 64 + kh * 16) ^ ((pp & 7) << 4)));
  f32x4 acc[8];
  #pragma unroll
  for (int nt = 0; nt < 8; ++nt) acc[nt] = {0.f, 0.f, 0.f, 0.f};
  #pragma unroll
  for (int kt = 0; kt < 2; ++kt)
    #pragma unroll
    for (int nt = 0; nt < 8; ++nt) {
      int n = nt * 16 + col;
      bf16x8 wf = *(const bf16x8*)(wbytes + n * 128 +
                      ((kt * 64 + kh * 16) ^ ((n & 7) << 4)));
      acc[nt] = __builtin_amdgcn_mfma_f32_16x16x32_bf16(wf, xa[kt], acc[nt], 0, 0, 0);
    }

  // h1^T store: lane holds h1[pp][n' = nt*16+kh*4+rg] -> b64 stores
  #pragma unroll
  for (int nt = 0; nt < 8; ++nt) {
    f32x4u bias = *(const f32x4u*)(b1 + nt * 16 + kh * 4);
    uint32_t lo = pack_bf16(fmaxf(acc[nt][0] + bias.x, 0.0f),
                            fmaxf(acc[nt][1] + bias.y, 0.0f));
    uint32_t hi = pack_bf16(fmaxf(acc[nt][2] + bias.z, 0.0f),
                            fmaxf(acc[nt][3] + bias.w, 0.0f));
    u32x2 v; v.x = lo; v.y = hi;
    *(u32x2*)(hb + pp * 256 + ((nt * 32 + kh * 8) ^ ((pp & 7) << 4))) = v;
  }
  // wave-local RAW on hb: ds ops complete per-wave; no cross-wave sharing.

  // layer 2
  f32x4 acc2[8];
  #pragma unroll
  for (int nt = 0; nt < 8; ++nt) acc2[nt] = {0.f, 0.f, 0.f, 0.f};
  #pragma unroll
  for (int q = 0; q < 4; ++q) {
    bf16x8 ha = *(const bf16x8*)(hb + pp * 256 +
                    ((q * 64 + kh * 16) ^ ((pp & 7) << 4)));
    #pragma unroll
    for (int nt = 0; nt < 8; ++nt) {
      int n = nt * 16 + col;
      bf16x8 wf = *(const bf16x8*)(wbytes + 16384 + n * 256 +
                      ((q * 64 + kh * 16) ^ ((n & 7) << 4)));
      acc2[nt] = __builtin_amdgcn_mfma_f32_16x16x32_bf16(ha, wf, acc2[nt], 0, 0, 0);
    }
  }

  // layer 3: out = relu(h2) @ W3 + b3 (VALU + 16-lane butterfly)
  float osum[4] = {0.f, 0.f, 0.f, 0.f};
  #pragma unroll
  for (int nt = 0; nt < 8; ++nt) {
    float bias = b2[nt * 16 + col];
    float w3v = W3[nt * 16 + col];
    #pragma unroll
    for (int rg = 0; rg < 4; ++rg)
      osum[rg] = fmaf(fmaxf(acc2[nt][rg] + bias, 0.0f), w3v, osum[rg]);
  }
  #pragma unroll
  for (int rg = 0; rg < 4; ++rg) {
    osum[rg] += __shfl_xor(osum[rg], 1);
    osum[rg] += __shfl_xor(osum[rg], 2);
    osum[rg] += __shfl_xor(osum[rg], 4);
    osum[rg] += __shfl_xor(osum[rg], 8);
  }
  const float b3v = b3[0];
  #pragma unroll
  for (int rg = 0; rg < 4; ++rg) {
    if (col == rg) {
      int pr = base + w * 16 + kh * 4 + rg;
      if (pr < count) out[pr] = osum[rg] + b3v;
    }
  }
}

extern "C" void kernel_launch(void* const* d_in, const int* in_sizes, int n_in,
                              void* d_out, int out_size, void* d_ws, size_t ws_size,
                              hipStream_t stream) {
  const float* x   = (const float*)d_in[0];
  const float* emb = (const float*)d_in[1];
  const float* W1  = (const float*)d_in[2];
  const float* b1  = (const float*)d_in[3];
  const float* W2  = (const float*)d_in[4];
  const float* b2  = (const float*)d_in[5];
  const float* W3  = (const float*)d_in[6];
  const float* b3  = (const float*)d_in[7];
  float* out = (float*)d_out;
  const int N = in_sizes[0] / 3;

  uint16_t* wimg = (uint16_t*)d_ws;   // 48KB prebaked W image

  Scales sc;
  for (int l = 0; l < NLV; ++l)
    sc.s[l] = (float)(exp2((double)l) - 1.0);  // matches reference f64 math

  prep_kernel<<<48, 512, 0, stream>>>(W1, W2, wimg);
  fused_kernel<<<(N + 63) / 64, 256, 0, stream>>>(
      x, emb, wimg, b1, b2, W3, b3, out, N, sc);
}

// Round 11
// 937.259 us; speedup vs baseline: 2.0551x; 2.0551x over previous
//
#include <hip/hip_runtime.h>
#include <stdint.h>

// Instant-NGP hash-grid + MLP, level-partitioned two-kernel structure.
// encode: HASH levels 7..30 only (3 per XCD, L2-owned), corner-pair gathers.
// mlp (round-8 proven structure): W images staged to LDS once per block from
//   prebaked wimg; staging phase ALSO computes dense levels 0-6 and hash
//   level 31 inline (idle-TA work); 2 barriers/group.

#define NLV 32
#define LOG2T 19
#define TSZ (1u << LOG2T)
#define TMASK (TSZ - 1u)
#define PRIME2 2654435761u
#define PRIME3 805459861u
#define NHASH 24   // levels 7..30 in encode kernel; feats idx = l-7

typedef float v2f __attribute__((ext_vector_type(2)));
typedef float f32x4 __attribute__((ext_vector_type(4)));
typedef float f32x4u __attribute__((ext_vector_type(4), aligned(8)));
typedef short bf16x8 __attribute__((ext_vector_type(8)));
typedef uint32_t u32x4 __attribute__((ext_vector_type(4)));

__device__ __forceinline__ uint32_t pack_bf16(float a, float b) {
  uint32_t ua = __float_as_uint(a), ub = __float_as_uint(b);
  ua = (ua + 0x7fffu + ((ua >> 16) & 1u)) >> 16;
  ub = (ub + 0x7fffu + ((ub >> 16) & 1u)) >> 16;
  return ua | (ub << 16);
}
__device__ __forceinline__ uint16_t bf16_rne(float a) {
  uint32_t u = __float_as_uint(a);
  u = (u + 0x7fffu + ((u >> 16) & 1u)) >> 16;
  return (uint16_t)u;
}

// one level's trilinear-interp feature pair, bit-exact vs reference
__device__ __forceinline__ uint32_t encode_level(
    float scale, uint32_t r, bool dense, const v2f* __restrict__ embl,
    float xv, float yv, float zv)
{
  // EXACT reference rounding: mul RN then add RN (no FMA contraction!)
  float px = __fadd_rn(__fmul_rn(xv, scale), 0.5f);
  float py = __fadd_rn(__fmul_rn(yv, scale), 0.5f);
  float pz = __fadd_rn(__fmul_rn(zv, scale), 0.5f);
  float bx = floorf(px), by = floorf(py), bz = floorf(pz);
  float fx = __fsub_rn(px, bx), fy = __fsub_rn(py, by), fz = __fsub_rn(pz, bz);
  uint32_t gx = (uint32_t)bx, gy = (uint32_t)by, gz = (uint32_t)bz;
  float wx0 = __fsub_rn(1.0f, fx), wx1 = fx;
  float wy0 = __fsub_rn(1.0f, fy), wy1 = fy;
  float wz0 = __fsub_rn(1.0f, fz), wz1 = fz;
  const uint32_t rr = r * r;

  float f0 = 0.0f, f1 = 0.0f;
  #pragma unroll
  for (int cp = 0; cp < 4; ++cp) {
    uint32_t cy = gy + (uint32_t)(cp & 1);
    uint32_t cz = gz + (uint32_t)(cp >> 1);
    float wyz = __fmul_rn((cp & 1) ? wy1 : wy0, (cp >> 1) ? wz1 : wz0);
    v2f e0, e1;
    if (dense) {
      uint32_t i0 = gx + cy * r + cz * rr;      // idx1 = idx0 + 1
      f32x4 e2 = *(const f32x4u*)&embl[i0];
      e0[0] = e2.x; e0[1] = e2.y; e1[0] = e2.z; e1[1] = e2.w;
    } else {
      uint32_t h = (cy * PRIME2) ^ (cz * PRIME3);
      uint32_t i0 = (gx ^ h) & TMASK;
      if (!(gx & 1u)) {                          // idx1 = idx0 ^ 1
        f32x4 e2 = *(const f32x4*)&embl[i0 & ~1u];
        bool odd = (i0 & 1u) != 0u;
        e0[0] = odd ? e2.z : e2.x; e0[1] = odd ? e2.w : e2.y;
        e1[0] = odd ? e2.x : e2.z; e1[1] = odd ? e2.y : e2.w;
      } else {
        uint32_t i1 = ((gx + 1u) ^ h) & TMASK;
        e0 = embl[i0];
        e1 = embl[i1];
      }
    }
    float w0 = __fmul_rn(wx0, wyz), w1 = __fmul_rn(wx1, wyz);
    f0 = fmaf(w0, e0[0], f0); f1 = fmaf(w0, e0[1], f1);
    f0 = fmaf(w1, e1[0], f0); f1 = fmaf(w1, e1[1], f1);
  }
  return pack_bf16(f0, f1);
}

__global__ __launch_bounds__(256) void encode_kernel(
    const float* __restrict__ x, const float* __restrict__ emb,
    uint32_t* __restrict__ feats, int offset, int count, int chunkCap, int bpl)
{
  const int bid = (int)blockIdx.x;
  const int xcd = bid & 7;
  const int j = bid >> 3;
  const int phase = j / bpl;              // 0..2
  const int within = j - phase * bpl;
  const int l = 7 + xcd + (phase << 3);   // hash levels 7..30, 3 per XCD

  const float scale = (float)((double)(1ULL << l) - 1.0);
  const v2f* __restrict__ embl = (const v2f*)(emb + ((size_t)l << (LOG2T + 1)));

  #pragma unroll
  for (int k = 0; k < 4; ++k) {
    int li = within * 1024 + k * 256 + (int)threadIdx.x;
    if (li < count) {
      int p = offset + li;
      float xv = __builtin_nontemporal_load(&x[3 * p + 0]);
      float yv = __builtin_nontemporal_load(&x[3 * p + 1]);
      float zv = __builtin_nontemporal_load(&x[3 * p + 2]);
      uint32_t f = encode_level(scale, 0u, false, embl, xv, yv, zv);
      __builtin_nontemporal_store(f, &feats[(size_t)(l - 7) * chunkCap + li]);
    }
  }
}

// W1 -> wimg[0..16KB): byte addr n*128 + ((k*2)^((n&7)<<4))
// W2 -> wimg[16KB..48KB): byte addr 16384 + n*256 + ((k*2)^((n&7)<<4))
__global__ __launch_bounds__(512) void prep_kernel(
    const float* __restrict__ W1, const float* __restrict__ W2,
    uint16_t* __restrict__ wimg)
{
  int i = (int)blockIdx.x * 512 + (int)threadIdx.x;
  if (i < 8192) {
    int k = i >> 7, n = i & 127;
    wimg[(n * 128 + ((k * 2) ^ ((n & 7) << 4))) >> 1] = bf16_rne(W1[i]);
  } else if (i < 24576) {
    int t = i - 8192;
    int k = t >> 7, n = t & 127;
    wimg[(16384 + n * 256 + ((k * 2) ^ ((n & 7) << 4))) >> 1] = bf16_rne(W2[t]);
  }
}

#define MLP_G 64   // points per group

__global__ __launch_bounds__(256, 2) void mlp_kernel(
    const float* __restrict__ x, const float* __restrict__ emb,
    const uint32_t* __restrict__ feats, const uint16_t* __restrict__ wimg,
    const float* __restrict__ b1, const float* __restrict__ b2,
    const float* __restrict__ W3, const float* __restrict__ b3,
    float* __restrict__ out, int offset, int count, int chunkCap, int nGroups)
{
  __shared__ char lds[65536];
  char* xh  = lds;           // 64 pts x 256B (X bf16x64 then h1 bf16x128)
  char* wt1 = lds + 16384;   // W1^T image, 16KB
  char* wb  = lds + 32768;   // W2^T image, 32KB

  const int tid = (int)threadIdx.x;
  const int lane = tid & 63;
  const int w = tid >> 6;      // wave 0..3
  const int col = lane & 15;
  const int kh = lane >> 4;

  // stage both W images once per block (swizzle baked into wimg)
  #pragma unroll
  for (int jj = 0; jj < 12; ++jj) {
    int i = tid + jj * 256;    // 3072 x 16B = 48KB
    ((u32x4*)wt1)[i] = ((const u32x4*)wimg)[i];
  }

  const int pp = w * 16 + col;
  float bias1[8], bias2[8], w3v[8];
  #pragma unroll
  for (int nt = 0; nt < 8; ++nt) {
    int n = nt * 16 + col;
    bias1[nt] = b1[n]; bias2[nt] = b2[n]; w3v[nt] = W3[n];
  }
  const float b3v = b3[0];

  const int sp = tid & 63;     // staging point
  const int sq = tid >> 6;     // staging quarter: planes sq*8..sq*8+7

  for (int g = (int)blockIdx.x; g < nGroups; g += (int)gridDim.x) {
    const int base = g * MLP_G;
    __syncthreads();  // W ready (first iter) / prev group's xh reads drained

    // ---- stage X: planes sq*8..+7 of point sp ----
    {
      int gp = base + sp;
      int src = (gp < count) ? gp : 0;
      u32x4 v0, v1;
      if (sq == 0) {
        // levels 0..6 computed inline (dense, tiny tables), level 7 from feats
        float xv = x[3 * src + 0], yv = x[3 * src + 1], zv = x[3 * src + 2];
        uint32_t f[7];
        #pragma unroll
        for (int l = 0; l < 7; ++l) {
          const float scale = (float)((double)(1ULL << l) - 1.0); // folds
          const v2f* embl = (const v2f*)(emb + ((size_t)l << (LOG2T + 1)));
          f[l] = encode_level(scale, 1u << l, true, embl, xv, yv, zv);
        }
        v0.x = f[0]; v0.y = f[1]; v0.z = f[2]; v0.w = f[3];
        v1.x = f[4]; v1.y = f[5]; v1.z = f[6];
        v1.w = __builtin_nontemporal_load(&feats[(size_t)0 * chunkCap + src]);
      } else if (sq == 3) {
        // levels 24..30 from feats (idx 17..23), level 31 computed inline
        float xv = x[3 * src + 0], yv = x[3 * src + 1], zv = x[3 * src + 2];
        v0.x = __builtin_nontemporal_load(&feats[(size_t)17 * chunkCap + src]);
        v0.y = __builtin_nontemporal_load(&feats[(size_t)18 * chunkCap + src]);
        v0.z = __builtin_nontemporal_load(&feats[(size_t)19 * chunkCap + src]);
        v0.w = __builtin_nontemporal_load(&feats[(size_t)20 * chunkCap + src]);
        v1.x = __builtin_nontemporal_load(&feats[(size_t)21 * chunkCap + src]);
        v1.y = __builtin_nontemporal_load(&feats[(size_t)22 * chunkCap + src]);
        v1.z = __builtin_nontemporal_load(&feats[(size_t)23 * chunkCap + src]);
        const float s31 = (float)((double)(1ULL << 31) - 1.0);
        const v2f* embl = (const v2f*)(emb + ((size_t)31 << (LOG2T + 1)));
        v1.w = encode_level(s31, 0u, false, embl, xv, yv, zv);
      } else {
        // sq=1: levels 8..15 (idx 1..8); sq=2: levels 16..23 (idx 9..16)
        int ib = sq * 8 - 7;
        v0.x = __builtin_nontemporal_load(&feats[(size_t)(ib + 0) * chunkCap + src]);
        v0.y = __builtin_nontemporal_load(&feats[(size_t)(ib + 1) * chunkCap + src]);
        v0.z = __builtin_nontemporal_load(&feats[(size_t)(ib + 2) * chunkCap + src]);
        v0.w = __builtin_nontemporal_load(&feats[(size_t)(ib + 3) * chunkCap + src]);
        v1.x = __builtin_nontemporal_load(&feats[(size_t)(ib + 4) * chunkCap + src]);
        v1.y = __builtin_nontemporal_load(&feats[(size_t)(ib + 5) * chunkCap + src]);
        v1.z = __builtin_nontemporal_load(&feats[(size_t)(ib + 6) * chunkCap + src]);
        v1.w = __builtin_nontemporal_load(&feats[(size_t)(ib + 7) * chunkCap + src]);
      }
      int sw = (sp & 7) << 4;
      *(u32x4*)(xh + sp * 256 + ((sq * 32 +  0) ^ sw)) = v0;
      *(u32x4*)(xh + sp * 256 + ((sq * 32 + 16) ^ sw)) = v1;
    }
    __syncthreads();

    // ---- layer 1: h1[p][n] = relu(X @ W1 + b1) ----
    f32x4 acc[8];
    #pragma unroll
    for (int nt = 0; nt < 8; ++nt) acc[nt] = {0.f, 0.f, 0.f, 0.f};
    #pragma unroll
    for (int kt = 0; kt < 2; ++kt) {
      bf16x8 a = *(const bf16x8*)(xh + pp * 256 + ((kt * 64 + kh * 16) ^ ((pp & 7) << 4)));
      #pragma unroll
      for (int nt = 0; nt < 8; ++nt) {
        int n = nt * 16 + col;
        bf16x8 b = *(const bf16x8*)(wt1 + n * 128 + ((kt * 64 + kh * 16) ^ ((n & 7) << 4)));
        acc[nt] = __builtin_amdgcn_mfma_f32_16x16x32_bf16(a, b, acc[nt], 0, 0, 0);
      }
    }

    // h1 -> xh rows w*16..w*16+15 (wave-local: only this wave reads them)
    #pragma unroll
    for (int nt = 0; nt < 8; ++nt) {
      int n = nt * 16 + col;
      #pragma unroll
      for (int rg = 0; rg < 4; ++rg) {
        int pr = w * 16 + kh * 4 + rg;
        float h = fmaxf(acc[nt][rg] + bias1[nt], 0.0f);
        *(uint16_t*)(xh + pr * 256 + ((n * 2) ^ ((pr & 7) << 4))) = bf16_rne(h);
      }
    }
    // no barrier: h1 rows are wave-local (validated round 10)

    // ---- layer 2 (full W2 resident in LDS) ----
    f32x4 acc2[8];
    #pragma unroll
    for (int nt = 0; nt < 8; ++nt) acc2[nt] = {0.f, 0.f, 0.f, 0.f};
    #pragma unroll
    for (int q = 0; q < 4; ++q) {
      bf16x8 a = *(const bf16x8*)(xh + pp * 256 + ((q * 64 + kh * 16) ^ ((pp & 7) << 4)));
      #pragma unroll
      for (int nt = 0; nt < 8; ++nt) {
        int n = nt * 16 + col;
        bf16x8 b = *(const bf16x8*)(wb + n * 256 + ((q * 64 + kh * 16) ^ ((n & 7) << 4)));
        acc2[nt] = __builtin_amdgcn_mfma_f32_16x16x32_bf16(a, b, acc2[nt], 0, 0, 0);
      }
    }

    // ---- layer 3: out = relu(h2) @ W3 + b3 ----
    float osum[4] = {0.f, 0.f, 0.f, 0.f};
    #pragma unroll
    for (int nt = 0; nt < 8; ++nt) {
      #pragma unroll
      for (int rg = 0; rg < 4; ++rg)
        osum[rg] = fmaf(fmaxf(acc2[nt][rg] + bias2[nt], 0.0f), w3v[nt], osum[rg]);
    }
    #pragma unroll
    for (int rg = 0; rg < 4; ++rg) {
      osum[rg] += __shfl_xor(osum[rg], 1);
      osum[rg] += __shfl_xor(osum[rg], 2);
      osum[rg] += __shfl_xor(osum[rg], 4);
      osum[rg] += __shfl_xor(osum[rg], 8);
    }
    #pragma unroll
    for (int rg = 0; rg < 4; ++rg) {
      if (col == rg) {
        int pr = base + w * 16 + kh * 4 + rg;
        if (pr < count) out[offset + pr] = osum[rg] + b3v;
      }
    }
  }
}

extern "C" void kernel_launch(void* const* d_in, const int* in_sizes, int n_in,
                              void* d_out, int out_size, void* d_ws, size_t ws_size,
                              hipStream_t stream) {
  const float* x   = (const float*)d_in[0];
  const float* emb = (const float*)d_in[1];
  const float* W1  = (const float*)d_in[2];
  const float* b1  = (const float*)d_in[3];
  const float* W2  = (const float*)d_in[4];
  const float* b2  = (const float*)d_in[5];
  const float* W3  = (const float*)d_in[6];
  const float* b3  = (const float*)d_in[7];
  float* out = (float*)d_out;
  const int N = in_sizes[0] / 3;

  uint16_t* wimg = (uint16_t*)d_ws;                         // 48KB W image
  uint32_t* feats = (uint32_t*)((char*)d_ws + 49152);
  const size_t perPoint = (size_t)NHASH * sizeof(uint32_t); // 96 B/point
  size_t avail = (ws_size > 49152) ? ws_size - 49152 : 0;
  size_t capz = avail / perPoint;
  if (capz > (size_t)N) capz = (size_t)N;
  int cap = (int)capz & ~1023;
  if (cap <= 0) cap = (N < 1024) ? N : 1024;

  prep_kernel<<<48, 512, 0, stream>>>(W1, W2, wimg);

  for (int off = 0; off < N; off += cap) {
    int cnt = (N - off < cap) ? (N - off) : cap;
    int bpl = (cnt + 1023) / 1024;            // blocks per level
    encode_kernel<<<NHASH * bpl, 256, 0, stream>>>(x, emb, feats, off, cnt, cap, bpl);
    int nGroups = (cnt + MLP_G - 1) / MLP_G;
    int nb = nGroups < 2048 ? nGroups : 2048;
    mlp_kernel<<<nb, 256, 0, stream>>>(
        x, emb, feats, wimg, b1, b2, W3, b3, out, off, cnt, cap, nGroups);
  }
}